// Round 11
// baseline (916.839 us; speedup 1.0000x reference)
//
#include <hip/hip_runtime.h>
#include <cstdint>
#include <cstddef>

typedef unsigned long long u64;
typedef unsigned int u32;

#define NANCHORS 39375
#define PRE_NMS  2000
#define POST_NMS 300
#define CAND_CAP 4096
#define UNEG 0x007FFFFFu   // f2u(-inf)

__device__ __forceinline__ u32 f2u(float f) {
  u32 u = __float_as_uint(f);
  return (u & 0x80000000u) ? ~u : (u | 0x80000000u);
}

// ---------------- fused utility: zero h accumulator + weight transpose + anchor copy ----
// grid = 6563 (zero, float4) + 144 (wtrans 64x64 tiles) + 154 (anchor copy, float4)
__global__ __launch_bounds__(256) void util_kernel(
    float* __restrict__ hb,
    const float* __restrict__ w, float* __restrict__ wt,
    const float* __restrict__ anchors, float* __restrict__ out_anchors)
{
  int bid = blockIdx.x;
  if (bid < 6563) {
    // zero 6,720,000 floats = 1,680,000 float4
    int idx = bid * 256 + threadIdx.x;
    if (idx < 1680000) ((float4*)hb)[idx] = make_float4(0.f, 0.f, 0.f, 0.f);
  } else if (bid < 6563 + 144) {
    // w: [256 co][2304 r] -> wt: [2304 r][256 co]
    __shared__ float tile[64][65];
    int id = bid - 6563;
    int bx = id % 36, by = id / 36;
    int tx = threadIdx.x & 63, ty = threadIdx.x >> 6;
#pragma unroll
    for (int i = 0; i < 16; ++i) {
      int co = by * 64 + ty + i * 4;
      tile[ty + i * 4][tx] = w[(size_t)co * 2304 + bx * 64 + tx];
    }
    __syncthreads();
#pragma unroll
    for (int i = 0; i < 16; ++i) {
      int r = bx * 64 + ty + i * 4;
      wt[(size_t)r * 256 + by * 64 + tx] = tile[tx][ty + i * 4];
    }
  } else {
    // anchors copy: 157500 floats = 39375 float4
    int t = (bid - 6707) * 256 + threadIdx.x;
    if (t < 39375) ((float4*)out_anchors)[t] = ((const float4*)anchors)[t];
  }
}

// ---------------- conv 3x3 + bias (partial over ci-half), atomicAdd into zeroed h ------
// R7-exact (best measured: 469us, VALUBusy 73.6%, Occ 38%): grid (444, batch, ci-half),
// block=256 (one co/thread); tile 8x4; halo 6x10 padded rows 12; ci-half = 128 channels
// staged in 2 sub-chunks of 64 (LDS 18432B). h = bias + two commutative atomics.
__global__ __launch_bounds__(256) void conv_kernel(
    const float* __restrict__ f0, const float* __restrict__ f1, const float* __restrict__ f2,
    const float* __restrict__ wt, const float* __restrict__ bias, float* __restrict__ hbase)
{
  __shared__ __align__(16) float lds[64 * 72];
  int b = blockIdx.y;
  int ch = blockIdx.z;
  int t = blockIdx.x;
  int H, W, tiles_x; const float* x; size_t hoff;
  if (t < 325)      { H = 100; W = 100; tiles_x = 13; x = f0; hoff = 0; }
  else if (t < 416) { H = 50;  W = 50;  tiles_x = 7;  x = f1; hoff = 5120000; t -= 325; }
  else              { H = 25;  W = 25;  tiles_x = 4;  x = f2; hoff = 6400000; t -= 416; }
  float* out = hbase + hoff;

  int tyi = t / tiles_x, txi = t % tiles_x;
  int y0 = tyi * 4, x0 = txi * 8;
  int HW = H * W;
  const float* xb = x + (size_t)b * 256 * HW + (size_t)ch * 128 * HW;

  int co = threadIdx.x;
  float acc[32];
  float bv = (ch == 0) ? bias[co] : 0.f;
#pragma unroll
  for (int p = 0; p < 32; ++p) acc[p] = bv;

  const float* wp = wt + co + (size_t)ch * 128 * 9 * 256;

  for (int sub = 0; sub < 2; ++sub) {
    const float* xc = xb + (size_t)sub * 64 * HW;
    for (int tt = threadIdx.x; tt < 64 * 60; tt += 256) {
      int ci = tt / 60, p = tt % 60;
      int hy = p / 10, hx = p % 10;
      int gy = y0 + hy - 1, gx = x0 + hx - 1;
      float v = 0.f;
      if (gy >= 0 && gy < H && gx >= 0 && gx < W)
        v = xc[((size_t)ci * H + gy) * W + gx];
      lds[ci * 72 + hy * 12 + hx] = v;
    }
    __syncthreads();

    const float* wsub = wp + (size_t)sub * 64 * 9 * 256;
#pragma unroll 2
    for (int cl = 0; cl < 64; ++cl) {
      const float* base = lds + cl * 72;
      const float* wrow = wsub + (size_t)cl * 9 * 256;
      float wr[9];
#pragma unroll
      for (int k = 0; k < 9; ++k) wr[k] = wrow[k * 256];
#pragma unroll
      for (int r = 0; r < 6; ++r) {
        float4 q0 = *(const float4*)(base + r * 12 + 0);
        float4 q1 = *(const float4*)(base + r * 12 + 4);
        float2 q2 = *(const float2*)(base + r * 12 + 8);
        float pxl[10] = {q0.x, q0.y, q0.z, q0.w, q1.x, q1.y, q1.z, q1.w, q2.x, q2.y};
#pragma unroll
        for (int dy = 0; dy < 3; ++dy) {
          int py = r - dy;
          if (py >= 0 && py < 4) {
            float w0 = wr[dy * 3 + 0], w1 = wr[dy * 3 + 1], w2 = wr[dy * 3 + 2];
#pragma unroll
            for (int px = 0; px < 8; ++px) {
              float a = acc[py * 8 + px];
              a = fmaf(w0, pxl[px + 0], a);
              a = fmaf(w1, pxl[px + 1], a);
              a = fmaf(w2, pxl[px + 2], a);
              acc[py * 8 + px] = a;
            }
          }
        }
      }
    }
    __syncthreads();
  }

#pragma unroll
  for (int py = 0; py < 4; ++py) {
#pragma unroll
    for (int px = 0; px < 8; ++px) {
      int gy = y0 + py, gx = x0 + px;
      if (gy < H && gx < W)
        atomicAdd(&out[((size_t)b * HW + gy * W + gx) * 256 + co], acc[py * 8 + px]);
    }
  }
}

// ---------------- heads (all levels): relu + 1x1 loc/score, softmax fg, decode, key ----
__global__ __launch_bounds__(256) void head_kernel(
    const float* __restrict__ hbase, const float* __restrict__ loc_w, const float* __restrict__ loc_b,
    const float* __restrict__ score_w, const float* __restrict__ score_b,
    const float* __restrict__ anchors, const int* __restrict__ imgh, const int* __restrict__ imgw,
    float* __restrict__ out_locs, float* __restrict__ out_scores,
    float* __restrict__ boxes, u32* __restrict__ ukey)
{
  int wid = (blockIdx.x * blockDim.x + threadIdx.x) >> 6;
  int lane = threadIdx.x & 63;
  if (wid >= 2 * 13125) return;
  int b = wid / 13125, r = wid % 13125;
  int HW, pos, base_row; size_t hoff;
  if (r < 10000)      { HW = 10000; pos = r;         base_row = 0;     hoff = 0; }
  else if (r < 12500) { HW = 2500;  pos = r - 10000; base_row = 30000; hoff = 5120000; }
  else                { HW = 625;   pos = r - 12500; base_row = 37500; hoff = 6400000; }

  const float4* hp = (const float4*)(hbase + hoff + ((size_t)b * HW + pos) * 256);
  float4 hv = hp[lane];
  hv.x = fmaxf(hv.x, 0.f); hv.y = fmaxf(hv.y, 0.f);
  hv.z = fmaxf(hv.z, 0.f); hv.w = fmaxf(hv.w, 0.f);

  float s[18];
#pragma unroll
  for (int o = 0; o < 12; ++o) {
    float4 wv = ((const float4*)(loc_w + o * 256))[lane];
    s[o] = hv.x * wv.x + hv.y * wv.y + hv.z * wv.z + hv.w * wv.w;
  }
#pragma unroll
  for (int o = 0; o < 6; ++o) {
    float4 wv = ((const float4*)(score_w + o * 256))[lane];
    s[12 + o] = hv.x * wv.x + hv.y * wv.y + hv.z * wv.z + hv.w * wv.w;
  }
#pragma unroll
  for (int off = 32; off > 0; off >>= 1) {
#pragma unroll
    for (int o = 0; o < 18; ++o) s[o] += __shfl_xor(s[o], off, 64);
  }

  if (lane < 3) {
    int a = lane;
    float l0 = s[4*a+0] + loc_b[4*a+0];
    float l1 = s[4*a+1] + loc_b[4*a+1];
    float l2 = s[4*a+2] + loc_b[4*a+2];
    float l3 = s[4*a+3] + loc_b[4*a+3];
    float sc0 = s[12+2*a+0] + score_b[2*a+0];
    float sc1 = s[12+2*a+1] + score_b[2*a+1];

    int row = base_row + pos * 3 + a;
    size_t g = (size_t)b * NANCHORS + row;
    out_locs[g*4+0] = l0; out_locs[g*4+1] = l1; out_locs[g*4+2] = l2; out_locs[g*4+3] = l3;
    out_scores[g*2+0] = sc0; out_scores[g*2+1] = sc1;

    float mx = fmaxf(sc0, sc1);
    float e0 = expf(sc0 - mx), e1 = expf(sc1 - mx);
    float fg = e1 / (e0 + e1);

    const float* an = anchors + (size_t)row * 4;
    float a0 = an[0], a1 = an[1], a2 = an[2], a3 = an[3];
    float sh = a2 - a0, sw = a3 - a1;
    float cy = a0 + 0.5f * sh, cx = a1 + 0.5f * sw;
    float ncy = l0 * sh + cy, ncx = l1 * sw + cx;
    float nh = expf(l2) * sh, nw = expf(l3) * sw;
    float IH = (float)(*imgh), IW = (float)(*imgw);
    float y1 = fminf(fmaxf(ncy - 0.5f * nh, 0.f), IH);
    float x1 = fminf(fmaxf(ncx - 0.5f * nw, 0.f), IW);
    float y2 = fminf(fmaxf(ncy + 0.5f * nh, 0.f), IH);
    float x2 = fminf(fmaxf(ncx + 0.5f * nw, 0.f), IW);
    bool valid = ((y2 - y1) >= 16.0f) && ((x2 - x1) >= 16.0f);
    float scm = valid ? fg : -__builtin_inff();

    boxes[g*4+0] = y1; boxes[g*4+1] = x1; boxes[g*4+2] = y2; boxes[g*4+3] = x2;
    ukey[g] = f2u(scm);
  }
}

// ---------------- FUSED radix-select + bitonic sort (LDS union; no global cand) ---------
// phase 1: 4-pass radix select of 2000th-largest key (per-wave privatized histograms)
// phase 2: compact candidates straight into LDS key[]; bitonic sort desc by (score,~idx)
// phase 3: emit topbox + initial suppression mask sup0
__global__ __launch_bounds__(1024) void selsort_kernel(
    const u32* __restrict__ ukey, const float* __restrict__ boxes,
    float* __restrict__ topbox, u64* __restrict__ sup0)
{
  int b = blockIdx.x, tid = threadIdx.x;
  int wv = tid >> 6;
  const u32* u = ukey + (size_t)b * NANCHORS;

  __shared__ __align__(16) char smem[CAND_CAP * 8 + 2048];   // 34816 B
  u32 (*hist)[256] = (u32(*)[256])smem;                       // 16*256*4 = 16384 B
  u32* scan = (u32*)(smem + 16384);                           // 1024 B
  u64* key = (u64*)smem;                                      // 32768 B (aliases hist/scan)
  unsigned char* validf = (unsigned char*)(smem + CAND_CAP * 8); // 2048 B
  __shared__ u32 sh_prefix;
  __shared__ int sh_rem;
  __shared__ int sh_cnt;

  // ---- phase 1: radix select ----
  u32 prefix = 0; int rem = PRE_NMS;
  for (int pass = 0; pass < 4; ++pass) {
    int shift = 24 - 8 * pass;
    for (int i = tid; i < 16 * 256; i += 1024) ((u32*)hist)[i] = 0;
    __syncthreads();
    u32 himask = (pass == 0) ? 0u : (0xFFFFFFFFu << (shift + 8));
    for (int i = tid; i < NANCHORS; i += 1024) {
      u32 v = u[i];
      if ((v & himask) == (prefix & himask))
        atomicAdd(&hist[wv][(v >> shift) & 255u], 1u);
    }
    __syncthreads();
    if (tid < 256) {
      u32 s = 0;
#pragma unroll
      for (int k = 0; k < 16; ++k) s += hist[k][tid];
      scan[tid] = s;
    }
    __syncthreads();
    for (int off = 1; off < 256; off <<= 1) {
      u32 v = 0, add = 0;
      if (tid < 256) { v = scan[tid]; if (tid + off < 256) add = scan[tid + off]; }
      __syncthreads();
      if (tid < 256) scan[tid] = v + add;
      __syncthreads();
    }
    if (tid < 256) {
      int s = (int)scan[tid];
      int snext = (tid < 255) ? (int)scan[tid + 1] : 0;
      if (s >= rem && snext < rem) { sh_prefix = prefix | ((u32)tid << shift); sh_rem = rem - snext; }
    }
    __syncthreads();
    prefix = sh_prefix; rem = sh_rem;
    __syncthreads();
  }

  // ---- phase 2: compact into LDS key[], then bitonic sort ----
  for (int t = tid; t < CAND_CAP; t += 1024) key[t] = 0ull;
  if (tid == 0) sh_cnt = 0;
  __syncthreads();
  for (int i = tid; i < NANCHORS; i += 1024) {
    u32 v = u[i];
    if (v >= prefix) {
      int p = atomicAdd(&sh_cnt, 1);
      if (p < CAND_CAP)
        key[p] = ((u64)v << 32) | (u32)(~(u32)i);
    }
  }
  __syncthreads();
  int cnt = sh_cnt;

  u32 n = (cnt <= 2048) ? 2048u : (u32)CAND_CAP;
  for (u32 k = 2; k <= n; k <<= 1) {
    for (u32 j = k >> 1; j > 0; j >>= 1) {
      __syncthreads();
      for (u32 t = tid; t < n; t += 1024) {
        u32 ixj = t ^ j;
        if (ixj > t) {
          u64 a = key[t], c = key[ixj];
          bool desc = ((t & k) == 0);
          if (desc ? (a < c) : (a > c)) { key[t] = c; key[ixj] = a; }
        }
      }
    }
  }
  __syncthreads();

  // ---- phase 3: topbox + sup0 ----
  for (int t = tid; t < 2048; t += 1024) {
    unsigned char vf = 0;
    if (t < PRE_NMS) {
      u64 kk = key[t];
      u32 uu = (u32)(kk >> 32);
      float* tb = topbox + ((size_t)b * PRE_NMS + t) * 4;
      if (uu != 0u) {
        u32 idx = ~((u32)kk);
        const float* bp = boxes + ((size_t)b * NANCHORS + idx) * 4;
        tb[0] = bp[0]; tb[1] = bp[1]; tb[2] = bp[2]; tb[3] = bp[3];
        vf = (uu != UNEG) ? 1 : 0;
      } else {
        tb[0] = 0.f; tb[1] = 0.f; tb[2] = 0.f; tb[3] = 0.f;
      }
    }
    validf[t] = vf;
  }
  __syncthreads();
  if (tid < 32) {
    u64 m = 0;
    for (int bit = 0; bit < 64; ++bit) {
      int j = tid * 64 + bit;
      if (j >= PRE_NMS || !validf[j]) m |= (1ull << bit);
    }
    sup0[b * 32 + tid] = m;
  }
}

// ---------------- pairwise IoU suppression bitmask ----------------
__global__ __launch_bounds__(256) void iou_kernel(const float* __restrict__ topbox, u64* __restrict__ M)
{
  int t = blockIdx.x * 256 + threadIdx.x;   // < 2000*32
  int b = blockIdx.y;
  int i = t >> 5, w = t & 31;
  const float* tb = topbox + (size_t)b * PRE_NMS * 4;
  const float* bi = tb + (size_t)i * 4;
  float iy1 = bi[0], ix1 = bi[1], iy2 = bi[2], ix2 = bi[3];
  float ai = (iy2 - iy1) * (ix2 - ix1);
  u64 m = 0;
  for (int bit = 0; bit < 64; ++bit) {
    int j = w * 64 + bit;
    if (j < PRE_NMS && j > i) {
      const float* bj = tb + (size_t)j * 4;
      float ty = fmaxf(iy1, bj[0]), tx = fmaxf(ix1, bj[1]);
      float by = fminf(iy2, bj[2]), bx = fminf(ix2, bj[3]);
      float hh = fmaxf(by - ty, 0.f), ww = fmaxf(bx - tx, 0.f);
      float inter = hh * ww;
      float aj = (bj[2] - bj[0]) * (bj[3] - bj[1]);
      float iou = inter / (ai + aj - inter + 1e-12f);
      if (iou > 0.7f) m |= (1ull << bit);
    }
  }
  M[((size_t)b * PRE_NMS + i) * 32 + w] = m;
}

// ---------------- FUSED block-sequential NMS scan + final emit ----------------
// 320 threads: wave 0 (tid<64) runs the NMS scan; all threads hit barriers; then all
// 320 emit the first 300 kept boxes + roi indices. supf lives in LDS only.
__global__ __launch_bounds__(320) void nmsfinal_kernel(
    const u64* __restrict__ M, const u64* __restrict__ sup0,
    const float* __restrict__ topbox, float* __restrict__ rois, float* __restrict__ roiidx)
{
  int b = blockIdx.x, tid = threadIdx.x;
  __shared__ u64 D[64];
  __shared__ u64 supw[32];
  __shared__ int ord[POST_NMS];
  __shared__ int cnt_s;
  const u64* Mb = M + (size_t)b * PRE_NMS * 32;

  int lane = tid & 63;
  int wl = lane & 31;
  int half = lane >> 5;
  u64 sup = 0;
  if (tid < 64) sup = sup0[b * 32 + wl];     // replicated in both lane halves

  for (int cb = 0; cb < 32; ++cb) {
    int row0 = cb << 6;
    if (tid < 64) {
      int row = row0 + lane;
      D[lane] = (row < PRE_NMS) ? Mb[(size_t)row * 32 + cb] : 0ull;
    }
    __syncthreads();
    if (tid < 64) {
      u64 S = __shfl(sup, cb, 64);
#pragma unroll
      for (int j = 0; j < 64; ++j) {
        u64 mask = ((S >> j) & 1ull) - 1ull;   // all-ones if row j kept
        S |= mask & D[j];
      }
      if (wl == cb) sup = S;
      u64 acc = 0;
#pragma unroll
      for (int jj = 0; jj < 32; ++jj) {
        int j = (jj << 1) | half;
        int row = row0 + j;
        u64 v = (row < PRE_NMS) ? Mb[(size_t)row * 32 + wl] : 0ull;
        u64 mask = ((S >> j) & 1ull) - 1ull;
        acc |= mask & v;
      }
      acc |= __shfl_xor(acc, 32, 64);
      sup |= acc;
    }
    __syncthreads();
  }
  if (tid < 32) supw[tid] = sup;
  __syncthreads();

  // final emit
  if (tid == 0) {
    int cnt = 0;
    for (int w = 0; w < 32 && cnt < POST_NMS; ++w) {
      u64 kept = ~supw[w];
      while (kept && cnt < POST_NMS) {
        int bit = __builtin_ctzll(kept); kept &= kept - 1;
        ord[cnt++] = w * 64 + bit;
      }
    }
    cnt_s = cnt;
  }
  __syncthreads();
  if (tid < POST_NMS) {
    float v0 = 0.f, v1 = 0.f, v2 = 0.f, v3 = 0.f;
    if (tid < cnt_s) {
      const float* tb = topbox + ((size_t)b * PRE_NMS + ord[tid]) * 4;
      v0 = tb[0]; v1 = tb[1]; v2 = tb[2]; v3 = tb[3];
    }
    float* r = rois + ((size_t)b * POST_NMS + tid) * 4;
    r[0] = v0; r[1] = v1; r[2] = v2; r[3] = v3;
    roiidx[b * POST_NMS + tid] = (float)b;
  }
}

extern "C" void kernel_launch(void* const* d_in, const int* in_sizes, int n_in,
                              void* d_out, int out_size, void* d_ws, size_t ws_size,
                              hipStream_t stream) {
  const float* feat0   = (const float*)d_in[0];
  const float* feat1   = (const float*)d_in[1];
  const float* feat2   = (const float*)d_in[2];
  const float* conv_w  = (const float*)d_in[3];
  const float* conv_b  = (const float*)d_in[4];
  const float* score_w = (const float*)d_in[5];
  const float* score_b = (const float*)d_in[6];
  const float* loc_w   = (const float*)d_in[7];
  const float* loc_b   = (const float*)d_in[8];
  const float* anchors = (const float*)d_in[9];
  const int*   img_h   = (const int*)d_in[10];
  const int*   img_w   = (const int*)d_in[11];

  float* out_f       = (float*)d_out;
  float* out_locs    = out_f;                // 2*39375*4
  float* out_scores  = out_f + 315000;       // 2*39375*2
  float* out_rois    = out_f + 472500;       // 600*4
  float* out_roiidx  = out_f + 474900;       // 600
  float* out_anchors = out_f + 475500;       // 39375*4

  char* p = (char*)d_ws;
  float* hb = (float*)p;      p += (size_t)6720000 * 4;   // h accumulator (zeroed by util)
  float* wtr = (float*)p;     p += (size_t)589824 * 4;    // transposed conv weights
  float* boxes = (float*)p;   p += (size_t)315000 * 4;    // 2*39375*4
  u32* ukey = (u32*)p;        p += (size_t)78750 * 4;     // 2*39375
  float* topbox = (float*)p;  p += (size_t)16000 * 4;     // 2*2000*4
  u64* Mrows = (u64*)p;       p += (size_t)128000 * 8;    // 2*2000*32
  u64* sup0 = (u64*)p;        p += 64 * 8;

  util_kernel<<<6861, 256, 0, stream>>>(hb, conv_w, wtr, anchors, out_anchors);
  conv_kernel<<<dim3(444, 2, 2), 256, 0, stream>>>(feat0, feat1, feat2, wtr, conv_b, hb);
  head_kernel<<<6563, 256, 0, stream>>>(
      hb, loc_w, loc_b, score_w, score_b, anchors, img_h, img_w,
      out_locs, out_scores, boxes, ukey);
  selsort_kernel<<<2, 1024, 0, stream>>>(ukey, boxes, topbox, sup0);
  iou_kernel<<<dim3(250, 2), 256, 0, stream>>>(topbox, Mrows);
  nmsfinal_kernel<<<2, 320, 0, stream>>>(Mrows, sup0, topbox, out_rois, out_roiidx);
}

// Round 12
// 763.285 us; speedup vs baseline: 1.2012x; 1.2012x over previous
//
#include <hip/hip_runtime.h>
#include <cstdint>
#include <cstddef>

typedef unsigned long long u64;
typedef unsigned int u32;

#define NANCHORS 39375
#define PRE_NMS  2000
#define POST_NMS 300
#define CAND_CAP 4096
#define UNEG 0x007FFFFFu   // f2u(-inf)

__device__ __forceinline__ u32 f2u(float f) {
  u32 u = __float_as_uint(f);
  return (u & 0x80000000u) ? ~u : (u | 0x80000000u);
}

// ---------------- weight transpose (LDS-tiled, coalesced both sides) -------------------
// w: [256 co][2304 r] -> wt: [2304 r][256 co].  grid (36,4), 256 thr.
__global__ __launch_bounds__(256) void wtrans_kernel(const float* __restrict__ w, float* __restrict__ wt) {
  __shared__ float tile[64][65];
  int bx = blockIdx.x, by = blockIdx.y;
  int tx = threadIdx.x & 63, ty = threadIdx.x >> 6;
#pragma unroll
  for (int i = 0; i < 16; ++i) {
    int co = by * 64 + ty + i * 4;
    tile[ty + i * 4][tx] = w[(size_t)co * 2304 + bx * 64 + tx];
  }
  __syncthreads();
#pragma unroll
  for (int i = 0; i < 16; ++i) {
    int r = bx * 64 + ty + i * 4;
    wt[(size_t)r * 256 + by * 64 + tx] = tile[tx][ty + i * 4];
  }
}

// ---------------- conv 3x3 + bias (partial over ci-half), atomicAdd into zeroed h ------
// R7-exact (best measured: 469us, VALUBusy 73.6%, Occ 38%): grid (444, batch, ci-half),
// block=256 (one co/thread); tile 8x4; halo 6x10 padded rows 12; ci-half = 128 channels
// staged in 2 sub-chunks of 64 (LDS 18432B). h = bias + two commutative atomics.
// NOTE (journal): this structure is LDS-pipe-bound — per wave per ci, 18 ds_read instrs
// (~144 pipe cyc) x 4 SIMDs saturate the CU LDS pipe against 576 FMA issue cyc. Tile-shape
// variants (2-co/128thr, tile-pair, 8x8/acc64) all regressed (R8/R9/R10). Do not re-tune.
__global__ __launch_bounds__(256) void conv_kernel(
    const float* __restrict__ f0, const float* __restrict__ f1, const float* __restrict__ f2,
    const float* __restrict__ wt, const float* __restrict__ bias, float* __restrict__ hbase)
{
  __shared__ __align__(16) float lds[64 * 72];
  int b = blockIdx.y;
  int ch = blockIdx.z;
  int t = blockIdx.x;
  int H, W, tiles_x; const float* x; size_t hoff;
  if (t < 325)      { H = 100; W = 100; tiles_x = 13; x = f0; hoff = 0; }
  else if (t < 416) { H = 50;  W = 50;  tiles_x = 7;  x = f1; hoff = 5120000; t -= 325; }
  else              { H = 25;  W = 25;  tiles_x = 4;  x = f2; hoff = 6400000; t -= 416; }
  float* out = hbase + hoff;

  int tyi = t / tiles_x, txi = t % tiles_x;
  int y0 = tyi * 4, x0 = txi * 8;
  int HW = H * W;
  const float* xb = x + (size_t)b * 256 * HW + (size_t)ch * 128 * HW;

  int co = threadIdx.x;
  float acc[32];
  float bv = (ch == 0) ? bias[co] : 0.f;
#pragma unroll
  for (int p = 0; p < 32; ++p) acc[p] = bv;

  const float* wp = wt + co + (size_t)ch * 128 * 9 * 256;

  for (int sub = 0; sub < 2; ++sub) {
    const float* xc = xb + (size_t)sub * 64 * HW;
    for (int tt = threadIdx.x; tt < 64 * 60; tt += 256) {
      int ci = tt / 60, p = tt % 60;
      int hy = p / 10, hx = p % 10;
      int gy = y0 + hy - 1, gx = x0 + hx - 1;
      float v = 0.f;
      if (gy >= 0 && gy < H && gx >= 0 && gx < W)
        v = xc[((size_t)ci * H + gy) * W + gx];
      lds[ci * 72 + hy * 12 + hx] = v;
    }
    __syncthreads();

    const float* wsub = wp + (size_t)sub * 64 * 9 * 256;
#pragma unroll 2
    for (int cl = 0; cl < 64; ++cl) {
      const float* base = lds + cl * 72;
      const float* wrow = wsub + (size_t)cl * 9 * 256;
      float wr[9];
#pragma unroll
      for (int k = 0; k < 9; ++k) wr[k] = wrow[k * 256];
#pragma unroll
      for (int r = 0; r < 6; ++r) {
        float4 q0 = *(const float4*)(base + r * 12 + 0);
        float4 q1 = *(const float4*)(base + r * 12 + 4);
        float2 q2 = *(const float2*)(base + r * 12 + 8);
        float pxl[10] = {q0.x, q0.y, q0.z, q0.w, q1.x, q1.y, q1.z, q1.w, q2.x, q2.y};
#pragma unroll
        for (int dy = 0; dy < 3; ++dy) {
          int py = r - dy;
          if (py >= 0 && py < 4) {
            float w0 = wr[dy * 3 + 0], w1 = wr[dy * 3 + 1], w2 = wr[dy * 3 + 2];
#pragma unroll
            for (int px = 0; px < 8; ++px) {
              float a = acc[py * 8 + px];
              a = fmaf(w0, pxl[px + 0], a);
              a = fmaf(w1, pxl[px + 1], a);
              a = fmaf(w2, pxl[px + 2], a);
              acc[py * 8 + px] = a;
            }
          }
        }
      }
    }
    __syncthreads();
  }

#pragma unroll
  for (int py = 0; py < 4; ++py) {
#pragma unroll
    for (int px = 0; px < 8; ++px) {
      int gy = y0 + py, gx = x0 + px;
      if (gy < H && gx < W)
        atomicAdd(&out[((size_t)b * HW + gy * W + gx) * 256 + co], acc[py * 8 + px]);
    }
  }
}

// ---------------- heads (all levels): relu + 1x1 loc/score, softmax fg, decode, key ----
__global__ __launch_bounds__(256) void head_kernel(
    const float* __restrict__ hbase, const float* __restrict__ loc_w, const float* __restrict__ loc_b,
    const float* __restrict__ score_w, const float* __restrict__ score_b,
    const float* __restrict__ anchors, const int* __restrict__ imgh, const int* __restrict__ imgw,
    float* __restrict__ out_locs, float* __restrict__ out_scores,
    float* __restrict__ boxes, u32* __restrict__ ukey)
{
  int wid = (blockIdx.x * blockDim.x + threadIdx.x) >> 6;
  int lane = threadIdx.x & 63;
  if (wid >= 2 * 13125) return;
  int b = wid / 13125, r = wid % 13125;
  int HW, pos, base_row; size_t hoff;
  if (r < 10000)      { HW = 10000; pos = r;         base_row = 0;     hoff = 0; }
  else if (r < 12500) { HW = 2500;  pos = r - 10000; base_row = 30000; hoff = 5120000; }
  else                { HW = 625;   pos = r - 12500; base_row = 37500; hoff = 6400000; }

  const float4* hp = (const float4*)(hbase + hoff + ((size_t)b * HW + pos) * 256);
  float4 hv = hp[lane];
  hv.x = fmaxf(hv.x, 0.f); hv.y = fmaxf(hv.y, 0.f);
  hv.z = fmaxf(hv.z, 0.f); hv.w = fmaxf(hv.w, 0.f);

  float s[18];
#pragma unroll
  for (int o = 0; o < 12; ++o) {
    float4 wv = ((const float4*)(loc_w + o * 256))[lane];
    s[o] = hv.x * wv.x + hv.y * wv.y + hv.z * wv.z + hv.w * wv.w;
  }
#pragma unroll
  for (int o = 0; o < 6; ++o) {
    float4 wv = ((const float4*)(score_w + o * 256))[lane];
    s[12 + o] = hv.x * wv.x + hv.y * wv.y + hv.z * wv.z + hv.w * wv.w;
  }
#pragma unroll
  for (int off = 32; off > 0; off >>= 1) {
#pragma unroll
    for (int o = 0; o < 18; ++o) s[o] += __shfl_xor(s[o], off, 64);
  }

  if (lane < 3) {
    int a = lane;
    float l0 = s[4*a+0] + loc_b[4*a+0];
    float l1 = s[4*a+1] + loc_b[4*a+1];
    float l2 = s[4*a+2] + loc_b[4*a+2];
    float l3 = s[4*a+3] + loc_b[4*a+3];
    float sc0 = s[12+2*a+0] + score_b[2*a+0];
    float sc1 = s[12+2*a+1] + score_b[2*a+1];

    int row = base_row + pos * 3 + a;
    size_t g = (size_t)b * NANCHORS + row;
    out_locs[g*4+0] = l0; out_locs[g*4+1] = l1; out_locs[g*4+2] = l2; out_locs[g*4+3] = l3;
    out_scores[g*2+0] = sc0; out_scores[g*2+1] = sc1;

    float mx = fmaxf(sc0, sc1);
    float e0 = expf(sc0 - mx), e1 = expf(sc1 - mx);
    float fg = e1 / (e0 + e1);

    const float* an = anchors + (size_t)row * 4;
    float a0 = an[0], a1 = an[1], a2 = an[2], a3 = an[3];
    float sh = a2 - a0, sw = a3 - a1;
    float cy = a0 + 0.5f * sh, cx = a1 + 0.5f * sw;
    float ncy = l0 * sh + cy, ncx = l1 * sw + cx;
    float nh = expf(l2) * sh, nw = expf(l3) * sw;
    float IH = (float)(*imgh), IW = (float)(*imgw);
    float y1 = fminf(fmaxf(ncy - 0.5f * nh, 0.f), IH);
    float x1 = fminf(fmaxf(ncx - 0.5f * nw, 0.f), IW);
    float y2 = fminf(fmaxf(ncy + 0.5f * nh, 0.f), IH);
    float x2 = fminf(fmaxf(ncx + 0.5f * nw, 0.f), IW);
    bool valid = ((y2 - y1) >= 16.0f) && ((x2 - x1) >= 16.0f);
    float scm = valid ? fg : -__builtin_inff();

    boxes[g*4+0] = y1; boxes[g*4+1] = x1; boxes[g*4+2] = y2; boxes[g*4+3] = x2;
    ukey[g] = f2u(scm);
  }
}

// ---------------- copy anchors to output ----------------
__global__ void copyf_kernel(const float* __restrict__ a, float* __restrict__ o, int n) {
  int t = blockIdx.x * 256 + threadIdx.x;
  if (t < n) o[t] = a[t];
}

// ---------------- radix-select: per-wave privatized histograms (hot-bin contention /16) --
__global__ __launch_bounds__(1024) void select_kernel(
    const u32* __restrict__ ukey, u64* __restrict__ cand, int* __restrict__ candcnt)
{
  int b = blockIdx.x, tid = threadIdx.x;
  int wv = tid >> 6;
  const u32* u = ukey + (size_t)b * NANCHORS;
  __shared__ u32 hist[16][256];
  __shared__ u32 scan[256];
  __shared__ u32 sh_prefix;
  __shared__ int sh_rem;
  __shared__ int sh_cnt;

  u32 prefix = 0; int rem = PRE_NMS;
  for (int pass = 0; pass < 4; ++pass) {
    int shift = 24 - 8 * pass;
    for (int i = tid; i < 16 * 256; i += 1024) ((u32*)hist)[i] = 0;
    __syncthreads();
    u32 himask = (pass == 0) ? 0u : (0xFFFFFFFFu << (shift + 8));
    for (int i = tid; i < NANCHORS; i += 1024) {
      u32 v = u[i];
      if ((v & himask) == (prefix & himask))
        atomicAdd(&hist[wv][(v >> shift) & 255u], 1u);
    }
    __syncthreads();
    if (tid < 256) {
      u32 s = 0;
#pragma unroll
      for (int k = 0; k < 16; ++k) s += hist[k][tid];
      scan[tid] = s;
    }
    __syncthreads();
    for (int off = 1; off < 256; off <<= 1) {
      u32 v = 0, add = 0;
      if (tid < 256) { v = scan[tid]; if (tid + off < 256) add = scan[tid + off]; }
      __syncthreads();
      if (tid < 256) scan[tid] = v + add;
      __syncthreads();
    }
    if (tid < 256) {
      int s = (int)scan[tid];
      int snext = (tid < 255) ? (int)scan[tid + 1] : 0;
      if (s >= rem && snext < rem) { sh_prefix = prefix | ((u32)tid << shift); sh_rem = rem - snext; }
    }
    __syncthreads();
    prefix = sh_prefix; rem = sh_rem;
    __syncthreads();
  }

  if (tid == 0) sh_cnt = 0;
  __syncthreads();
  for (int i = tid; i < NANCHORS; i += 1024) {
    u32 v = u[i];
    if (v >= prefix) {
      int p = atomicAdd(&sh_cnt, 1);
      if (p < CAND_CAP)
        cand[(size_t)b * CAND_CAP + p] = ((u64)v << 32) | (u32)(~(u32)i);
    }
  }
  __syncthreads();
  if (tid == 0) candcnt[b] = (sh_cnt < CAND_CAP) ? sh_cnt : CAND_CAP;
}

// ---------------- bitonic sort candidates desc by (score, ~idx); emit top boxes + init mask
__global__ __launch_bounds__(1024) void sort_kernel(
    const u64* __restrict__ cand, const int* __restrict__ candcnt,
    const float* __restrict__ boxes, float* __restrict__ topbox, u64* __restrict__ sup0)
{
  int b = blockIdx.x, tid = threadIdx.x;
  __shared__ u64 key[CAND_CAP];
  __shared__ unsigned char validf[2048];
  int cnt = candcnt[b];
  for (int t = tid; t < CAND_CAP; t += 1024)
    key[t] = (t < cnt) ? cand[(size_t)b * CAND_CAP + t] : 0ull;
  __syncthreads();

  u32 n = (cnt <= 2048) ? 2048u : (u32)CAND_CAP;
  for (u32 k = 2; k <= n; k <<= 1) {
    for (u32 j = k >> 1; j > 0; j >>= 1) {
      __syncthreads();
      for (u32 t = tid; t < n; t += 1024) {
        u32 ixj = t ^ j;
        if (ixj > t) {
          u64 a = key[t], c = key[ixj];
          bool desc = ((t & k) == 0);
          if (desc ? (a < c) : (a > c)) { key[t] = c; key[ixj] = a; }
        }
      }
    }
  }
  __syncthreads();

  for (int t = tid; t < 2048; t += 1024) {
    unsigned char vf = 0;
    if (t < PRE_NMS) {
      u64 kk = key[t];
      u32 uu = (u32)(kk >> 32);
      float* tb = topbox + ((size_t)b * PRE_NMS + t) * 4;
      if (uu != 0u) {
        u32 idx = ~((u32)kk);
        const float* bp = boxes + ((size_t)b * NANCHORS + idx) * 4;
        tb[0] = bp[0]; tb[1] = bp[1]; tb[2] = bp[2]; tb[3] = bp[3];
        vf = (uu != UNEG) ? 1 : 0;
      } else {
        tb[0] = 0.f; tb[1] = 0.f; tb[2] = 0.f; tb[3] = 0.f;
      }
    }
    validf[t] = vf;
  }
  __syncthreads();
  if (tid < 32) {
    u64 m = 0;
    for (int bit = 0; bit < 64; ++bit) {
      int j = tid * 64 + bit;
      if (j >= PRE_NMS || !validf[j]) m |= (1ull << bit);
    }
    sup0[b * 32 + tid] = m;
  }
}

// ---------------- pairwise IoU suppression bitmask ----------------
__global__ __launch_bounds__(256) void iou_kernel(const float* __restrict__ topbox, u64* __restrict__ M)
{
  int t = blockIdx.x * 256 + threadIdx.x;   // < 2000*32
  int b = blockIdx.y;
  int i = t >> 5, w = t & 31;
  const float* tb = topbox + (size_t)b * PRE_NMS * 4;
  const float* bi = tb + (size_t)i * 4;
  float iy1 = bi[0], ix1 = bi[1], iy2 = bi[2], ix2 = bi[3];
  float ai = (iy2 - iy1) * (ix2 - ix1);
  u64 m = 0;
  for (int bit = 0; bit < 64; ++bit) {
    int j = w * 64 + bit;
    if (j < PRE_NMS && j > i) {
      const float* bj = tb + (size_t)j * 4;
      float ty = fmaxf(iy1, bj[0]), tx = fmaxf(ix1, bj[1]);
      float by = fminf(iy2, bj[2]), bx = fminf(ix2, bj[3]);
      float hh = fmaxf(by - ty, 0.f), ww = fmaxf(bx - tx, 0.f);
      float inter = hh * ww;
      float aj = (bj[2] - bj[0]) * (bj[3] - bj[1]);
      float iou = inter / (ai + aj - inter + 1e-12f);
      if (iou > 0.7f) m |= (1ull << bit);
    }
  }
  M[((size_t)b * PRE_NMS + i) * 32 + w] = m;
}

// ---------------- block-sequential NMS scan; row-OR as unrolled masked loads ------------
__global__ __launch_bounds__(64) void nms_kernel(
    const u64* __restrict__ M, const u64* __restrict__ sup0, u64* __restrict__ supf)
{
  int b = blockIdx.x;
  int lane = threadIdx.x;
  int wl = lane & 31;
  int half = lane >> 5;
  const u64* Mb = M + (size_t)b * PRE_NMS * 32;
  __shared__ u64 D[64];
  u64 sup = sup0[b * 32 + wl];             // replicated in both lane halves

  for (int cb = 0; cb < 32; ++cb) {
    int row0 = cb << 6;
    {
      int row = row0 + lane;
      D[lane] = (row < PRE_NMS) ? Mb[(size_t)row * 32 + cb] : 0ull;
    }
    __syncthreads();
    u64 S = __shfl(sup, cb, 64);
#pragma unroll
    for (int j = 0; j < 64; ++j) {
      u64 mask = ((S >> j) & 1ull) - 1ull;   // all-ones if row j kept
      S |= mask & D[j];
    }
    if (wl == cb) sup = S;
    u64 acc = 0;
#pragma unroll
    for (int jj = 0; jj < 32; ++jj) {
      int j = (jj << 1) | half;
      int row = row0 + j;
      u64 v = (row < PRE_NMS) ? Mb[(size_t)row * 32 + wl] : 0ull;
      u64 mask = ((S >> j) & 1ull) - 1ull;
      acc |= mask & v;
    }
    acc |= __shfl_xor(acc, 32, 64);
    sup |= acc;
    __syncthreads();
  }
  if (lane < 32) supf[b * 32 + lane] = sup;
}

// ---------------- emit first 300 kept boxes + roi indices ----------------
__global__ __launch_bounds__(320) void final_kernel(
    const u64* __restrict__ supf, const float* __restrict__ topbox,
    float* __restrict__ rois, float* __restrict__ roiidx)
{
  int b = blockIdx.x, tid = threadIdx.x;
  __shared__ int ord[POST_NMS];
  __shared__ int cnt_s;
  if (tid == 0) {
    int cnt = 0;
    for (int w = 0; w < 32 && cnt < POST_NMS; ++w) {
      u64 kept = ~supf[b * 32 + w];
      while (kept && cnt < POST_NMS) {
        int bit = __builtin_ctzll(kept); kept &= kept - 1;
        ord[cnt++] = w * 64 + bit;
      }
    }
    cnt_s = cnt;
  }
  __syncthreads();
  if (tid < POST_NMS) {
    float v0 = 0.f, v1 = 0.f, v2 = 0.f, v3 = 0.f;
    if (tid < cnt_s) {
      const float* tb = topbox + ((size_t)b * PRE_NMS + ord[tid]) * 4;
      v0 = tb[0]; v1 = tb[1]; v2 = tb[2]; v3 = tb[3];
    }
    float* r = rois + ((size_t)b * POST_NMS + tid) * 4;
    r[0] = v0; r[1] = v1; r[2] = v2; r[3] = v3;
    roiidx[b * POST_NMS + tid] = (float)b;
  }
}

extern "C" void kernel_launch(void* const* d_in, const int* in_sizes, int n_in,
                              void* d_out, int out_size, void* d_ws, size_t ws_size,
                              hipStream_t stream) {
  const float* feat0   = (const float*)d_in[0];
  const float* feat1   = (const float*)d_in[1];
  const float* feat2   = (const float*)d_in[2];
  const float* conv_w  = (const float*)d_in[3];
  const float* conv_b  = (const float*)d_in[4];
  const float* score_w = (const float*)d_in[5];
  const float* score_b = (const float*)d_in[6];
  const float* loc_w   = (const float*)d_in[7];
  const float* loc_b   = (const float*)d_in[8];
  const float* anchors = (const float*)d_in[9];
  const int*   img_h   = (const int*)d_in[10];
  const int*   img_w   = (const int*)d_in[11];

  float* out_f       = (float*)d_out;
  float* out_locs    = out_f;                // 2*39375*4
  float* out_scores  = out_f + 315000;       // 2*39375*2
  float* out_rois    = out_f + 472500;       // 600*4
  float* out_roiidx  = out_f + 474900;       // 600
  float* out_anchors = out_f + 475500;       // 39375*4

  char* p = (char*)d_ws;
  float* hb = (float*)p;      p += (size_t)6720000 * 4;   // h accumulator (zeroed)
  float* wtr = (float*)p;     p += (size_t)589824 * 4;    // transposed conv weights
  float* boxes = (float*)p;   p += (size_t)315000 * 4;    // 2*39375*4
  u32* ukey = (u32*)p;        p += (size_t)78750 * 4;     // 2*39375
  u64* cand = (u64*)p;        p += (size_t)2 * CAND_CAP * 8;
  int* candcnt = (int*)p;     p += 256;
  float* topbox = (float*)p;  p += (size_t)16000 * 4;     // 2*2000*4
  u64* Mrows = (u64*)p;       p += (size_t)128000 * 8;    // 2*2000*32
  u64* sup0 = (u64*)p;        p += 64 * 8;
  u64* supf = (u64*)p;        p += 64 * 8;

  hipMemsetAsync(hb, 0, (size_t)6720000 * 4, stream);
  wtrans_kernel<<<dim3(36, 4), 256, 0, stream>>>(conv_w, wtr);
  conv_kernel<<<dim3(444, 2, 2), 256, 0, stream>>>(feat0, feat1, feat2, wtr, conv_b, hb);
  head_kernel<<<6563, 256, 0, stream>>>(
      hb, loc_w, loc_b, score_w, score_b, anchors, img_h, img_w,
      out_locs, out_scores, boxes, ukey);
  copyf_kernel<<<(157500 + 255) / 256, 256, 0, stream>>>(anchors, out_anchors, 157500);
  select_kernel<<<2, 1024, 0, stream>>>(ukey, cand, candcnt);
  sort_kernel<<<2, 1024, 0, stream>>>(cand, candcnt, boxes, topbox, sup0);
  iou_kernel<<<dim3(250, 2), 256, 0, stream>>>(topbox, Mrows);
  nms_kernel<<<2, 64, 0, stream>>>(Mrows, sup0, supf);
  final_kernel<<<2, 320, 0, stream>>>(supf, topbox, out_rois, out_roiidx);
}